// Round 1
// baseline (9497.639 us; speedup 1.0000x reference)
//
#include <hip/hip_runtime.h>
#include <math.h>

#define BATCH 128
#define NDIM 512
#define POWER_ITERS 30
#define N_ITERS 500

// ---------------- helpers ----------------
__device__ __forceinline__ float4 ld4(const float* p) { return *(const float4*)p; }

__device__ __forceinline__ float4 f4_fma(float4 a, float s, float4 acc) {
  acc.x = fmaf(a.x, s, acc.x);
  acc.y = fmaf(a.y, s, acc.y);
  acc.z = fmaf(a.z, s, acc.z);
  acc.w = fmaf(a.w, s, acc.w);
  return acc;
}
__device__ __forceinline__ float4 f4_add(float4 a, float4 b) {
  return make_float4(a.x + b.x, a.y + b.y, a.z + b.z, a.w + b.w);
}
__device__ __forceinline__ float wave_sum64(float x) {
#pragma unroll
  for (int off = 1; off < 64; off <<= 1) x += __shfl_xor(x, off, 64);
  return x;
}

// ---------------- kernel 1: S = 0.5*(S + S^T), in place, idempotent ----------------
// grid (BATCH, 16, 16); block (32, 8). Tiled through LDS so transpose reads coalesce.
__global__ void symmetrize_kernel(float* __restrict__ S) {
  const int ti = blockIdx.y, tj = blockIdx.z;
  if (tj < ti) return;  // upper-triangle tile pairs only (handles both tiles)
  __shared__ float ta[32][33];
  __shared__ float tb[32][33];
  float* base = S + (size_t)blockIdx.x * NDIM * NDIM;
  const int tx = threadIdx.x;  // 0..31
  const int ty = threadIdx.y;  // 0..7
#pragma unroll
  for (int k = 0; k < 4; k++) {
    int r = ty + 8 * k;
    ta[r][tx] = base[(size_t)(ti * 32 + r) * NDIM + tj * 32 + tx];
    tb[r][tx] = base[(size_t)(tj * 32 + r) * NDIM + ti * 32 + tx];
  }
  __syncthreads();
#pragma unroll
  for (int k = 0; k < 4; k++) {
    int r = ty + 8 * k;
    base[(size_t)(ti * 32 + r) * NDIM + tj * 32 + tx] = 0.5f * (ta[r][tx] + tb[tx][r]);
  }
#pragma unroll
  for (int k = 0; k < 4; k++) {
    int r = ty + 8 * k;
    base[(size_t)(tj * 32 + r) * NDIM + ti * 32 + tx] = 0.5f * (tb[r][tx] + ta[tx][r]);
  }
}

// ---------------- matvec partial: z_partial[g] = S[g-slab]^T-free column form ----------------
// Column formulation (S symmetric): z[j] = sum_i S[i][j] * y[i].
// Group g (128 threads) covers i in [128g, 128g+128); thread owns columns 4c..4c+3.
__device__ __forceinline__ void matvec_partial(const float* __restrict__ Sb,
                                               const float* __restrict__ yv,
                                               float* __restrict__ zsc,
                                               int g, int c) {
  const float* rp = Sb + (size_t)(g * 128) * NDIM + 4 * c;
  const float* yp = yv + g * 128;
  float4 a0 = make_float4(0, 0, 0, 0), a1 = a0, a2 = a0, a3 = a0;
#pragma unroll 4
  for (int m = 0; m < 32; m++) {
    float4 yq = ld4(yp + 4 * m);  // LDS broadcast (wave-uniform address)
    float4 s0 = ld4(rp + (size_t)(4 * m + 0) * NDIM);
    float4 s1 = ld4(rp + (size_t)(4 * m + 1) * NDIM);
    float4 s2 = ld4(rp + (size_t)(4 * m + 2) * NDIM);
    float4 s3 = ld4(rp + (size_t)(4 * m + 3) * NDIM);
    a0 = f4_fma(s0, yq.x, a0);
    a1 = f4_fma(s1, yq.y, a1);
    a2 = f4_fma(s2, yq.z, a2);
    a3 = f4_fma(s3, yq.w, a3);
  }
  float4 z = f4_add(f4_add(a0, a1), f4_add(a2, a3));
  *(float4*)(zsc + g * NDIM + 4 * c) = z;
}

// combine 4 group-partials for wave0 lane's 8 columns (j = 8*lane .. 8*lane+7)
__device__ __forceinline__ void combine_z(const float* __restrict__ zsc, int lane, float* z8) {
#pragma unroll
  for (int q = 0; q < 2; q++) {
    float4 zz = ld4(zsc + 0 * NDIM + 8 * lane + 4 * q);
    zz = f4_add(zz, ld4(zsc + 1 * NDIM + 8 * lane + 4 * q));
    zz = f4_add(zz, ld4(zsc + 2 * NDIM + 8 * lane + 4 * q));
    zz = f4_add(zz, ld4(zsc + 3 * NDIM + 8 * lane + 4 * q));
    z8[4 * q + 0] = zz.x; z8[4 * q + 1] = zz.y;
    z8[4 * q + 2] = zz.z; z8[4 * q + 3] = zz.w;
  }
}

// ---------------- kernel 2: per-batch solver (one 512-thread block per batch) ----------------
__launch_bounds__(512, 1)
__global__ void qp_solver(const float* __restrict__ mu,
                          const float* __restrict__ S,
                          float* __restrict__ out) {
  __shared__ float yv[NDIM];       // current vector (b, then y)
  __shared__ float zsc[4 * NDIM];  // matvec partials per group
  __shared__ float bc[1];          // broadcast scalar (step)
  const int tid = threadIdx.x;
  const int g = tid >> 7;
  const int c = tid & 127;
  const int b = blockIdx.x;
  const float* Sb = S + (size_t)b * NDIM * NDIM;
  const float invn = 1.0f / (float)NDIM;

  yv[tid] = invn;  // b0 = 1/N
  __syncthreads();

  // ---- power iteration (30 steps) ----
  for (int it = 0; it < POWER_ITERS; it++) {
    matvec_partial(Sb, yv, zsc, g, c);
    __syncthreads();
    if (tid < 64) {
      float z8[8];
      combine_z(zsc, tid, z8);
      float ss = 0.f;
#pragma unroll
      for (int k = 0; k < 8; k++) ss += z8[k] * z8[k];
      ss = wave_sum64(ss);
      float inv = 1.0f / (sqrtf(ss) + 1e-12f);
      *(float4*)(yv + 8 * tid)     = make_float4(z8[0]*inv, z8[1]*inv, z8[2]*inv, z8[3]*inv);
      *(float4*)(yv + 8 * tid + 4) = make_float4(z8[4]*inv, z8[5]*inv, z8[6]*inv, z8[7]*inv);
    }
    __syncthreads();
  }

  // ---- lambda_max = b^T S b ; step = 1/(2*lmax + 1e-8) ----
  matvec_partial(Sb, yv, zsc, g, c);
  __syncthreads();
  if (tid < 64) {
    float z8[8];
    combine_z(zsc, tid, z8);
    float dd = 0.f;
#pragma unroll
    for (int k = 0; k < 8; k++) dd += z8[k] * yv[8 * tid + k];
    dd = wave_sum64(dd);
    if (tid == 0) bc[0] = 1.0f / (2.0f * dd + 1e-8f);
  }
  __syncthreads();

  // ---- FISTA init ----
  const float step = bc[0];
  yv[tid] = invn;  // y0 = w0 = 1/N  (safe: wave0's yv reads happened before the barrier)
  float w8[8], y8[8], mu8[8];
  if (tid < 64) {
#pragma unroll
    for (int k = 0; k < 8; k++) { w8[k] = invn; y8[k] = invn; }
    float4 m0 = ld4(mu + (size_t)b * NDIM + 8 * tid);
    float4 m1 = ld4(mu + (size_t)b * NDIM + 8 * tid + 4);
    mu8[0] = m0.x; mu8[1] = m0.y; mu8[2] = m0.z; mu8[3] = m0.w;
    mu8[4] = m1.x; mu8[5] = m1.y; mu8[6] = m1.z; mu8[7] = m1.w;
  }
  __syncthreads();

  float t = 1.0f;
  for (int it = 0; it < N_ITERS; it++) {
    matvec_partial(Sb, yv, zsc, g, c);  // z = S*y
    __syncthreads();
    if (tid < 64) {
      float z8[8], v8[8];
      combine_z(zsc, tid, z8);
#pragma unroll
      for (int k = 0; k < 8; k++)
        v8[k] = y8[k] - step * (2.0f * z8[k] - mu8[k]);

      // Michelot fixed-point: theta -> (sum_{v>theta} v - 1)/count, exact simplex proj.
      float th = -1e30f;
      for (int m = 0; m < 64; m++) {
        float s = 0.f, cn = 0.f;
#pragma unroll
        for (int k = 0; k < 8; k++)
          if (v8[k] > th) { s += v8[k]; cn += 1.f; }
#pragma unroll
        for (int off = 1; off < 64; off <<= 1) {
          s  += __shfl_xor(s, off, 64);
          cn += __shfl_xor(cn, off, 64);
        }
        float thn = (s - 1.0f) / cn;  // cn >= 1: th < theta* < max(v)
        if (!(thn > th)) break;       // converged (fp fixpoint)
        th = thn;
      }

      float tn = 0.5f * (1.0f + sqrtf(1.0f + 4.0f * t * t));
      float coef = (t - 1.0f) / tn;
      float yn[8];
#pragma unroll
      for (int k = 0; k < 8; k++) {
        float wn = fmaxf(v8[k] - th, 0.0f);
        yn[k] = wn + coef * (wn - w8[k]);
        w8[k] = wn;
        y8[k] = yn[k];
      }
      *(float4*)(yv + 8 * tid)     = make_float4(yn[0], yn[1], yn[2], yn[3]);
      *(float4*)(yv + 8 * tid + 4) = make_float4(yn[4], yn[5], yn[6], yn[7]);
      t = tn;
    }
    __syncthreads();
  }

  if (tid < 64) {
    *(float4*)(out + (size_t)b * NDIM + 8 * tid)     = make_float4(w8[0], w8[1], w8[2], w8[3]);
    *(float4*)(out + (size_t)b * NDIM + 8 * tid + 4) = make_float4(w8[4], w8[5], w8[6], w8[7]);
  }
}

// ---------------- launch ----------------
extern "C" void kernel_launch(void* const* d_in, const int* in_sizes, int n_in,
                              void* d_out, int out_size, void* d_ws, size_t ws_size,
                              hipStream_t stream) {
  const float* mu = (const float*)d_in[0];
  float* Sg = (float*)d_in[1];
  if (n_in >= 2 && in_sizes[0] > in_sizes[1]) {  // defensive: mu is the small input
    mu = (const float*)d_in[1];
    Sg = (float*)d_in[0];
  }
  float* out = (float*)d_out;

  // S = 0.5*(S + S^T) in place (idempotent, so safe under graph replay + restore)
  symmetrize_kernel<<<dim3(BATCH, 16, 16), dim3(32, 8), 0, stream>>>(Sg);
  // one block per batch instance
  qp_solver<<<dim3(BATCH), dim3(512), 0, stream>>>(mu, Sg, out);
}

// Round 2
// 3137.624 us; speedup vs baseline: 3.0270x; 3.0270x over previous
//
#include <hip/hip_runtime.h>
#include <hip/hip_fp16.h>
#include <math.h>

#define BATCH 128
#define NDIM 512
#define NPAIR 256          // row-pairs per batch
#define POWER_ITERS 30
#define N_ITERS 500
#define KEEP 32            // row-pairs per thread held in registers (of 64 owned)

typedef _Float16 half2_t __attribute__((ext_vector_type(2)));

union H2x4 { float4 f4; half2_t h[4]; };

// ---------------- helpers ----------------
__device__ __forceinline__ float4 ld4(const float* p) { return *(const float4*)p; }
__device__ __forceinline__ float4 f4_add(float4 a, float4 b) {
  return make_float4(a.x + b.x, a.y + b.y, a.z + b.z, a.w + b.w);
}
__device__ __forceinline__ float wave_sum64(float x) {
#pragma unroll
  for (int off = 1; off < 64; off <<= 1) x += __shfl_xor(x, off, 64);
  return x;
}
__device__ __forceinline__ float wave_max64(float x) {
#pragma unroll
  for (int off = 1; off < 64; off <<= 1) x = fmaxf(x, __shfl_xor(x, off, 64));
  return x;
}

// ============ fp16 path ============
// ---- conversion: Sh[b][pair][col] = half2( sym(2p,col), sym(2p+1,col) ) ----
__global__ void sym_conv_kernel(const float* __restrict__ S, half2_t* __restrict__ Sh) {
  const int bb = blockIdx.x, ti = blockIdx.y, tj = blockIdx.z;
  if (tj < ti) return;
  __shared__ float ta[32][33];
  __shared__ float tb[32][33];
  const float* base = S + (size_t)bb * NDIM * NDIM;
  half2_t* dst = Sh + (size_t)bb * NPAIR * NDIM;
  const int tx = threadIdx.x, ty = threadIdx.y;  // 32 x 8
#pragma unroll
  for (int k = 0; k < 4; k++) {
    int r = ty + 8 * k;
    ta[r][tx] = base[(size_t)(ti * 32 + r) * NDIM + tj * 32 + tx];
    tb[r][tx] = base[(size_t)(tj * 32 + r) * NDIM + ti * 32 + tx];
  }
  __syncthreads();
#pragma unroll
  for (int k = 0; k < 2; k++) {
    int pi = ty + 8 * k;  // local pair 0..15
    float v0 = 0.5f * (ta[2 * pi][tx] + tb[tx][2 * pi]);
    float v1 = 0.5f * (ta[2 * pi + 1][tx] + tb[tx][2 * pi + 1]);
    half2_t o; o[0] = (_Float16)v0; o[1] = (_Float16)v1;
    dst[(size_t)(ti * 16 + pi) * NDIM + tj * 32 + tx] = o;
  }
  if (ti != tj) {
#pragma unroll
    for (int k = 0; k < 2; k++) {
      int pi = ty + 8 * k;
      float v0 = 0.5f * (tb[2 * pi][tx] + ta[tx][2 * pi]);
      float v1 = 0.5f * (tb[2 * pi + 1][tx] + ta[tx][2 * pi + 1]);
      half2_t o; o[0] = (_Float16)v0; o[1] = (_Float16)v1;
      dst[(size_t)(tj * 16 + pi) * NDIM + ti * 32 + tx] = o;
    }
  }
}

// ---- matvec: acc over this thread's 64 pairs (KEEP from regs, rest streamed) ----
__device__ __forceinline__ float4 matvec_rs(const half2_t (&sreg)[KEEP * 4],
                                            const half2_t* __restrict__ Sb,
                                            const half2_t* __restrict__ ysh,
                                            int g, int c) {
  float a0 = 0.f, a1 = 0.f, a2 = 0.f, a3 = 0.f;
  const half2_t* ybase = ysh + 64 * g;
  // register-resident pairs
#pragma unroll
  for (int ch = 0; ch < KEEP / 4; ch++) {
    H2x4 y4; y4.f4 = *(const float4*)(ybase + 4 * ch);  // 4 pairs' y (uniform)
#pragma unroll
    for (int q = 0; q < 4; q++) {
      half2_t yy = y4.h[q];
      int p = 4 * ch + q;
      a0 = __builtin_amdgcn_fdot2(sreg[4 * p + 0], yy, a0, false);
      a1 = __builtin_amdgcn_fdot2(sreg[4 * p + 1], yy, a1, false);
      a2 = __builtin_amdgcn_fdot2(sreg[4 * p + 2], yy, a2, false);
      a3 = __builtin_amdgcn_fdot2(sreg[4 * p + 3], yy, a3, false);
    }
  }
  // streamed pairs (L2-resident working set: 256 KB/block)
  const half2_t* gp = Sb + (size_t)(64 * g + KEEP) * NDIM + 4 * c;
#pragma unroll 8
  for (int p = KEEP; p < 64; p++) {
    H2x4 s; s.f4 = *(const float4*)gp; gp += NDIM;
    half2_t yy = ybase[p];
    a0 = __builtin_amdgcn_fdot2(s.h[0], yy, a0, false);
    a1 = __builtin_amdgcn_fdot2(s.h[1], yy, a1, false);
    a2 = __builtin_amdgcn_fdot2(s.h[2], yy, a2, false);
    a3 = __builtin_amdgcn_fdot2(s.h[3], yy, a3, false);
  }
  return make_float4(a0, a1, a2, a3);
}

__device__ __forceinline__ void combine_z(const float* __restrict__ zsc, int lane, float* z8) {
#pragma unroll
  for (int q = 0; q < 2; q++) {
    float4 zz = ld4(zsc + 0 * NDIM + 8 * lane + 4 * q);
    zz = f4_add(zz, ld4(zsc + 1 * NDIM + 8 * lane + 4 * q));
    zz = f4_add(zz, ld4(zsc + 2 * NDIM + 8 * lane + 4 * q));
    zz = f4_add(zz, ld4(zsc + 3 * NDIM + 8 * lane + 4 * q));
    z8[4 * q + 0] = zz.x; z8[4 * q + 1] = zz.y;
    z8[4 * q + 2] = zz.z; z8[4 * q + 3] = zz.w;
  }
}

__device__ __forceinline__ void store_y_pairs(half2_t* ysh, int lane, const float* y8) {
  H2x4 yo;
#pragma unroll
  for (int q = 0; q < 4; q++) {
    half2_t v; v[0] = (_Float16)y8[2 * q]; v[1] = (_Float16)y8[2 * q + 1];
    yo.h[q] = v;
  }
  *(float4*)(ysh + 4 * lane) = yo.f4;
}

__launch_bounds__(512, 2)
__global__ void qp_solver_h(const float* __restrict__ mu,
                            const half2_t* __restrict__ Sh,
                            float* __restrict__ out) {
  __shared__ half2_t yh2[NPAIR];   // y as row-pairs (fp16)
  __shared__ float zsc[4 * NDIM];  // matvec partials per 128-thread group
  __shared__ int stopf;
  const int tid = threadIdx.x;
  const int g = tid >> 7;
  const int c = tid & 127;
  const int b = blockIdx.x;
  const half2_t* Sb = Sh + (size_t)b * NPAIR * NDIM;
  const float invn = 1.0f / (float)NDIM;

  // fill register-resident slab: pairs [64g, 64g+KEEP), cols 4c..4c+3
  half2_t sreg[KEEP * 4];
  {
    const half2_t* rp = Sb + (size_t)(64 * g) * NDIM + 4 * c;
#pragma unroll
    for (int p = 0; p < KEEP; p++) {
      H2x4 u; u.f4 = *(const float4*)(rp + (size_t)p * NDIM);
      sreg[4 * p + 0] = u.h[0]; sreg[4 * p + 1] = u.h[1];
      sreg[4 * p + 2] = u.h[2]; sreg[4 * p + 3] = u.h[3];
    }
  }
  if (tid < NPAIR) { half2_t v; v[0] = (_Float16)invn; v[1] = (_Float16)invn; yh2[tid] = v; }
  if (tid == 0) stopf = 0;
  __syncthreads();

  float y8[8];  // wave0 only: current vector fp32
  // ---- power iteration ----
  for (int it = 0; it < POWER_ITERS; it++) {
    float4 z = matvec_rs(sreg, Sb, yh2, g, c);
    *(float4*)(zsc + g * NDIM + 4 * c) = z;
    __syncthreads();
    if (tid < 64) {
      float z8[8];
      combine_z(zsc, tid, z8);
      float ss = 0.f;
#pragma unroll
      for (int k = 0; k < 8; k++) ss += z8[k] * z8[k];
      ss = wave_sum64(ss);
      float inv = 1.0f / (sqrtf(ss) + 1e-12f);
#pragma unroll
      for (int k = 0; k < 8; k++) y8[k] = z8[k] * inv;
      store_y_pairs(yh2, tid, y8);
    }
    __syncthreads();
  }

  // ---- lambda_max, step (wave0 registers) ----
  float step = 0.f;
  {
    float4 z = matvec_rs(sreg, Sb, yh2, g, c);
    *(float4*)(zsc + g * NDIM + 4 * c) = z;
    __syncthreads();
    if (tid < 64) {
      float z8[8];
      combine_z(zsc, tid, z8);
      float dd = 0.f;
#pragma unroll
      for (int k = 0; k < 8; k++) dd += z8[k] * y8[k];
      dd = wave_sum64(dd);
      step = 1.0f / (2.0f * dd + 1e-8f);
    }
    __syncthreads();
  }

  // ---- FISTA ----
  float w8[8], mu8[8];
  if (tid < 64) {
#pragma unroll
    for (int k = 0; k < 8; k++) { w8[k] = invn; y8[k] = invn; }
    float4 m0 = ld4(mu + (size_t)b * NDIM + 8 * tid);
    float4 m1 = ld4(mu + (size_t)b * NDIM + 8 * tid + 4);
    mu8[0] = m0.x; mu8[1] = m0.y; mu8[2] = m0.z; mu8[3] = m0.w;
    mu8[4] = m1.x; mu8[5] = m1.y; mu8[6] = m1.z; mu8[7] = m1.w;
  }
  if (tid < NPAIR) { half2_t v; v[0] = (_Float16)invn; v[1] = (_Float16)invn; yh2[tid] = v; }
  __syncthreads();

  float t = 1.0f;
  int streak = 0;
  for (int it = 0; it < N_ITERS; it++) {
    float4 z = matvec_rs(sreg, Sb, yh2, g, c);
    *(float4*)(zsc + g * NDIM + 4 * c) = z;
    __syncthreads();
    if (tid < 64) {
      float z8[8], v8[8];
      combine_z(zsc, tid, z8);
#pragma unroll
      for (int k = 0; k < 8; k++)
        v8[k] = y8[k] - step * (2.0f * z8[k] - mu8[k]);

      // Michelot fixed-point simplex projection
      float th = -1e30f;
      for (int m = 0; m < 64; m++) {
        float s = 0.f, cn = 0.f;
#pragma unroll
        for (int k = 0; k < 8; k++)
          if (v8[k] > th) { s += v8[k]; cn += 1.f; }
#pragma unroll
        for (int off = 1; off < 64; off <<= 1) {
          s  += __shfl_xor(s, off, 64);
          cn += __shfl_xor(cn, off, 64);
        }
        float thn = (s - 1.0f) / cn;
        if (!(thn > th)) break;
        th = thn;
      }

      float tn = 0.5f * (1.0f + sqrtf(1.0f + 4.0f * t * t));
      float coef = (t - 1.0f) / tn;
      float maxinc = 0.f;
#pragma unroll
      for (int k = 0; k < 8; k++) {
        float wn = fmaxf(v8[k] - th, 0.0f);
        maxinc = fmaxf(maxinc, fabsf(wn - w8[k]));
        y8[k] = wn + coef * (wn - w8[k]);
        w8[k] = wn;
      }
      t = tn;
      store_y_pairs(yh2, tid, y8);
      maxinc = wave_max64(maxinc);
      streak = (maxinc < 1e-7f) ? streak + 1 : 0;
      if (tid == 0 && streak >= 3) stopf = 1;
    }
    __syncthreads();
    if (stopf) break;
  }

  if (tid < 64) {
    *(float4*)(out + (size_t)b * NDIM + 8 * tid)     = make_float4(w8[0], w8[1], w8[2], w8[3]);
    *(float4*)(out + (size_t)b * NDIM + 8 * tid + 4) = make_float4(w8[4], w8[5], w8[6], w8[7]);
  }
}

// ============ fp32 fallback path (round-1, used only if ws too small) ============
__global__ void symmetrize_kernel(float* __restrict__ S) {
  const int ti = blockIdx.y, tj = blockIdx.z;
  if (tj < ti) return;
  __shared__ float ta[32][33];
  __shared__ float tb[32][33];
  float* base = S + (size_t)blockIdx.x * NDIM * NDIM;
  const int tx = threadIdx.x, ty = threadIdx.y;
#pragma unroll
  for (int k = 0; k < 4; k++) {
    int r = ty + 8 * k;
    ta[r][tx] = base[(size_t)(ti * 32 + r) * NDIM + tj * 32 + tx];
    tb[r][tx] = base[(size_t)(tj * 32 + r) * NDIM + ti * 32 + tx];
  }
  __syncthreads();
#pragma unroll
  for (int k = 0; k < 4; k++) {
    int r = ty + 8 * k;
    base[(size_t)(ti * 32 + r) * NDIM + tj * 32 + tx] = 0.5f * (ta[r][tx] + tb[tx][r]);
  }
#pragma unroll
  for (int k = 0; k < 4; k++) {
    int r = ty + 8 * k;
    base[(size_t)(tj * 32 + r) * NDIM + ti * 32 + tx] = 0.5f * (tb[r][tx] + ta[tx][r]);
  }
}

__device__ __forceinline__ float4 f4_fma(float4 a, float s, float4 acc) {
  acc.x = fmaf(a.x, s, acc.x); acc.y = fmaf(a.y, s, acc.y);
  acc.z = fmaf(a.z, s, acc.z); acc.w = fmaf(a.w, s, acc.w);
  return acc;
}
__device__ __forceinline__ void matvec_partial(const float* __restrict__ Sb,
                                               const float* __restrict__ yv,
                                               float* __restrict__ zsc, int g, int c) {
  const float* rp = Sb + (size_t)(g * 128) * NDIM + 4 * c;
  const float* yp = yv + g * 128;
  float4 a0 = make_float4(0, 0, 0, 0), a1 = a0, a2 = a0, a3 = a0;
#pragma unroll 4
  for (int m = 0; m < 32; m++) {
    float4 yq = ld4(yp + 4 * m);
    float4 s0 = ld4(rp + (size_t)(4 * m + 0) * NDIM);
    float4 s1 = ld4(rp + (size_t)(4 * m + 1) * NDIM);
    float4 s2 = ld4(rp + (size_t)(4 * m + 2) * NDIM);
    float4 s3 = ld4(rp + (size_t)(4 * m + 3) * NDIM);
    a0 = f4_fma(s0, yq.x, a0); a1 = f4_fma(s1, yq.y, a1);
    a2 = f4_fma(s2, yq.z, a2); a3 = f4_fma(s3, yq.w, a3);
  }
  float4 z = f4_add(f4_add(a0, a1), f4_add(a2, a3));
  *(float4*)(zsc + g * NDIM + 4 * c) = z;
}

__launch_bounds__(512, 1)
__global__ void qp_solver(const float* __restrict__ mu,
                          const float* __restrict__ S,
                          float* __restrict__ out) {
  __shared__ float yv[NDIM];
  __shared__ float zsc[4 * NDIM];
  __shared__ float bc[1];
  const int tid = threadIdx.x, g = tid >> 7, c = tid & 127, b = blockIdx.x;
  const float* Sb = S + (size_t)b * NDIM * NDIM;
  const float invn = 1.0f / (float)NDIM;
  yv[tid] = invn;
  __syncthreads();
  for (int it = 0; it < POWER_ITERS; it++) {
    matvec_partial(Sb, yv, zsc, g, c);
    __syncthreads();
    if (tid < 64) {
      float z8[8]; combine_z(zsc, tid, z8);
      float ss = 0.f;
#pragma unroll
      for (int k = 0; k < 8; k++) ss += z8[k] * z8[k];
      ss = wave_sum64(ss);
      float inv = 1.0f / (sqrtf(ss) + 1e-12f);
      *(float4*)(yv + 8 * tid)     = make_float4(z8[0]*inv, z8[1]*inv, z8[2]*inv, z8[3]*inv);
      *(float4*)(yv + 8 * tid + 4) = make_float4(z8[4]*inv, z8[5]*inv, z8[6]*inv, z8[7]*inv);
    }
    __syncthreads();
  }
  matvec_partial(Sb, yv, zsc, g, c);
  __syncthreads();
  if (tid < 64) {
    float z8[8]; combine_z(zsc, tid, z8);
    float dd = 0.f;
#pragma unroll
    for (int k = 0; k < 8; k++) dd += z8[k] * yv[8 * tid + k];
    dd = wave_sum64(dd);
    if (tid == 0) bc[0] = 1.0f / (2.0f * dd + 1e-8f);
  }
  __syncthreads();
  const float step = bc[0];
  yv[tid] = invn;
  float w8[8], y8[8], mu8[8];
  if (tid < 64) {
#pragma unroll
    for (int k = 0; k < 8; k++) { w8[k] = invn; y8[k] = invn; }
    float4 m0 = ld4(mu + (size_t)b * NDIM + 8 * tid);
    float4 m1 = ld4(mu + (size_t)b * NDIM + 8 * tid + 4);
    mu8[0] = m0.x; mu8[1] = m0.y; mu8[2] = m0.z; mu8[3] = m0.w;
    mu8[4] = m1.x; mu8[5] = m1.y; mu8[6] = m1.z; mu8[7] = m1.w;
  }
  __syncthreads();
  float t = 1.0f;
  for (int it = 0; it < N_ITERS; it++) {
    matvec_partial(Sb, yv, zsc, g, c);
    __syncthreads();
    if (tid < 64) {
      float z8[8], v8[8]; combine_z(zsc, tid, z8);
#pragma unroll
      for (int k = 0; k < 8; k++) v8[k] = y8[k] - step * (2.0f * z8[k] - mu8[k]);
      float th = -1e30f;
      for (int m = 0; m < 64; m++) {
        float s = 0.f, cn = 0.f;
#pragma unroll
        for (int k = 0; k < 8; k++) if (v8[k] > th) { s += v8[k]; cn += 1.f; }
#pragma unroll
        for (int off = 1; off < 64; off <<= 1) { s += __shfl_xor(s, off, 64); cn += __shfl_xor(cn, off, 64); }
        float thn = (s - 1.0f) / cn;
        if (!(thn > th)) break;
        th = thn;
      }
      float tn = 0.5f * (1.0f + sqrtf(1.0f + 4.0f * t * t));
      float coef = (t - 1.0f) / tn;
#pragma unroll
      for (int k = 0; k < 8; k++) {
        float wn = fmaxf(v8[k] - th, 0.0f);
        y8[k] = wn + coef * (wn - w8[k]);
        w8[k] = wn;
      }
      *(float4*)(yv + 8 * tid)     = make_float4(y8[0], y8[1], y8[2], y8[3]);
      *(float4*)(yv + 8 * tid + 4) = make_float4(y8[4], y8[5], y8[6], y8[7]);
      t = tn;
    }
    __syncthreads();
  }
  if (tid < 64) {
    *(float4*)(out + (size_t)b * NDIM + 8 * tid)     = make_float4(w8[0], w8[1], w8[2], w8[3]);
    *(float4*)(out + (size_t)b * NDIM + 8 * tid + 4) = make_float4(w8[4], w8[5], w8[6], w8[7]);
  }
}

// ---------------- launch ----------------
extern "C" void kernel_launch(void* const* d_in, const int* in_sizes, int n_in,
                              void* d_out, int out_size, void* d_ws, size_t ws_size,
                              hipStream_t stream) {
  const float* mu = (const float*)d_in[0];
  float* Sg = (float*)d_in[1];
  if (n_in >= 2 && in_sizes[0] > in_sizes[1]) { mu = (const float*)d_in[1]; Sg = (float*)d_in[0]; }
  float* out = (float*)d_out;

  const size_t need = (size_t)BATCH * NPAIR * NDIM * sizeof(half2_t);  // 64 MB
  if (ws_size >= need) {
    half2_t* Sh = (half2_t*)d_ws;
    sym_conv_kernel<<<dim3(BATCH, 16, 16), dim3(32, 8), 0, stream>>>(Sg, Sh);
    qp_solver_h<<<dim3(BATCH), dim3(512), 0, stream>>>(mu, Sh, out);
  } else {
    symmetrize_kernel<<<dim3(BATCH, 16, 16), dim3(32, 8), 0, stream>>>(Sg);
    qp_solver<<<dim3(BATCH), dim3(512), 0, stream>>>(mu, Sg, out);
  }
}